// Round 1
// baseline (333.331 us; speedup 1.0000x reference)
//
#include <hip/hip_runtime.h>

typedef _Float16 f16;
typedef _Float16 f16x8 __attribute__((ext_vector_type(8)));
typedef float f32x4 __attribute__((ext_vector_type(4)));

#define GLOBAL_AS __attribute__((address_space(1)))
#define LDS_AS __attribute__((address_space(3)))

// async global->LDS, 16B per lane. LDS dest = wave-uniform base + lane*16.
__device__ __forceinline__ void async16(const void* g, void* l) {
  __builtin_amdgcn_global_load_lds((const GLOBAL_AS unsigned int*)g,
                                   (LDS_AS unsigned int*)l, 16, 0, 0);
}

// ---------------- conversion kernels ----------------

// spikes fp32 [32768][784] -> f16 [32768][800] (pad cols 784..799 = 0)
// one thread per 8 output cols: 32768*100 threads
__global__ __launch_bounds__(256) void conv_a(const float* __restrict__ s,
                                              f16* __restrict__ a16) {
  int idx = blockIdx.x * 256 + threadIdx.x;  // < 3,276,800
  int m = idx / 100;
  int g = idx - m * 100;
  f16x8 h = {};
  if (g < 98) {
    const float4* p = (const float4*)(s + (size_t)m * 784 + g * 8);
    float4 x = p[0];
    float4 y = p[1];
    h[0] = (f16)x.x; h[1] = (f16)x.y; h[2] = (f16)x.z; h[3] = (f16)x.w;
    h[4] = (f16)y.x; h[5] = (f16)y.y; h[6] = (f16)y.z; h[7] = (f16)y.w;
  }
  *(f16x8*)(a16 + (size_t)m * 800 + g * 8) = h;
}

// w_hidden fp32 [512][784] -> f16 [512][1600]: cols 0..783 hi (pad->800),
// cols 800..1583 lo*2048 (pad->1600). One thread per output entry.
__global__ __launch_bounds__(256) void conv_wh(const float* __restrict__ w,
                                               f16* __restrict__ w2) {
  int idx = blockIdx.x * 256 + threadIdx.x;  // < 819,200
  int h = idx / 1600;
  int c = idx - h * 1600;
  f16 o = (f16)0.f;
  if (c < 784) {
    o = (f16)w[h * 784 + c];
  } else if (c >= 800 && c < 1584) {
    float x = w[h * 784 + (c - 800)];
    f16 hi = (f16)x;
    o = (f16)((x - (float)hi) * 2048.0f);  // exact residual, scaled out of denormal range
  }
  w2[idx] = o;
}

// w_out fp32 [128][512] -> f16 [128][1024]: cols 0..511 hi, 512..1023 lo*2048
__global__ __launch_bounds__(256) void conv_wo(const float* __restrict__ w,
                                               f16* __restrict__ w2) {
  int idx = blockIdx.x * 256 + threadIdx.x;  // < 131,072
  int o_ = idx >> 10;
  int c = idx & 1023;
  float x = w[o_ * 512 + (c & 511)];
  f16 hi = (f16)x;
  f16 r = (c < 512) ? hi : (f16)((x - (float)hi) * 2048.0f);
  w2[idx] = r;
}

// ---------------- split-precision f16 MFMA GEMM ----------------
// C[M][N_LD] = A[M][K] * B[N][K]^T with B holding (hi | lo*2048) planes.
// Phase 0 accumulates the lo plane, scales acc by 2^-11, phase 1 adds hi.
// 128x128 tile, BK=32, 4 waves in 2x2, 16x16x32 f16 MFMA (m97 structure).
template <int N_LD, int A_STRIDE, int B_STRIDE, int CHUNKS, int B_OFF_LO>
__global__ __launch_bounds__(256, 2) void gemm_split2(const f16* __restrict__ A,
                                                      const f16* __restrict__ B,
                                                      float* __restrict__ C) {
  __shared__ f16 lds_a[128 * 32];
  __shared__ f16 lds_b[128 * 32];
  const int t = threadIdx.x;
  const int lane = t & 63;
  const int wave = t >> 6;
  const int m0 = blockIdx.y * 128;
  const int n0 = blockIdx.x * 128;
  const int wm = (wave >> 1) * 64;
  const int wn = (wave & 1) * 64;
  const int row = lane & 15;
  const int quad = lane >> 4;

  // staging chunk assignment: chunk j covers LDS bytes [j*16, j*16+16),
  // i.e. tile row j>>2, col (j&3)*8 .. +8 (f16 elems)
  const int ja1 = t, ja2 = t + 256;
  const f16* a_base1 = A + (m0 + (ja1 >> 2)) * A_STRIDE + (ja1 & 3) * 8;
  const f16* a_base2 = A + (m0 + (ja2 >> 2)) * A_STRIDE + (ja2 & 3) * 8;
  const f16* b_base1 = B + (n0 + (ja1 >> 2)) * B_STRIDE + (ja1 & 3) * 8;
  const f16* b_base2 = B + (n0 + (ja2 >> 2)) * B_STRIDE + (ja2 & 3) * 8;

  f32x4 acc[4][4] = {};

  for (int phase = 0; phase < 2; ++phase) {
    const int boff = (phase == 0) ? B_OFF_LO : 0;
    for (int c = 0; c < CHUNKS; ++c) {
      const int k0 = c * 32;
      async16(a_base1 + k0, &lds_a[ja1 * 8]);
      async16(a_base2 + k0, &lds_a[ja2 * 8]);
      async16(b_base1 + boff + k0, &lds_b[ja1 * 8]);
      async16(b_base2 + boff + k0, &lds_b[ja2 * 8]);
      __syncthreads();
      f16x8 af[4], bf[4];
#pragma unroll
      for (int tm = 0; tm < 4; ++tm)
        af[tm] = *(const f16x8*)&lds_a[(wm + tm * 16 + row) * 32 + quad * 8];
#pragma unroll
      for (int tn = 0; tn < 4; ++tn)
        bf[tn] = *(const f16x8*)&lds_b[(wn + tn * 16 + row) * 32 + quad * 8];
#pragma unroll
      for (int tm = 0; tm < 4; ++tm)
#pragma unroll
        for (int tn = 0; tn < 4; ++tn)
          acc[tm][tn] =
              __builtin_amdgcn_mfma_f32_16x16x32_f16(af[tm], bf[tn], acc[tm][tn], 0, 0, 0);
      __syncthreads();
    }
    if (phase == 0) {
#pragma unroll
      for (int tm = 0; tm < 4; ++tm)
#pragma unroll
        for (int tn = 0; tn < 4; ++tn)
#pragma unroll
          for (int r = 0; r < 4; ++r) acc[tm][tn][r] *= 4.8828125e-4f;  // 2^-11, exact
    }
  }
  // C/D layout: col = lane&15, row = quad*4 + r
#pragma unroll
  for (int tm = 0; tm < 4; ++tm)
#pragma unroll
    for (int tn = 0; tn < 4; ++tn)
#pragma unroll
      for (int r = 0; r < 4; ++r) {
        const int mm = m0 + wm + tm * 16 + quad * 4 + r;
        const int nn = n0 + wn + tn * 16 + row;
        C[mm * N_LD + nn] = acc[tm][tn][r];
      }
}

// ---------------- CUBA LIF scan ----------------
// one thread per hidden neuron (b,h), sequential over T=256.
// c_h plane layout [t][65536] -> coalesced reads; writes f16 spikes in same layout.
__global__ __launch_bounds__(256) void lif_scan(const float* __restrict__ ch,
                                                f16* __restrict__ sh) {
  const int n = blockIdx.x * 256 + threadIdx.x;  // 65536 neurons
  float v = 0.f, cur = 0.f;
#pragma unroll 4
  for (int t = 0; t < 256; ++t) {
    float x = ch[t * 65536 + n];
    v = v + 0.16666667f * (cur - v);   // v += dt*tau_mem_inv*(-v+i), old i
    cur = 0.8333333f * cur + x;        // i = i*(1-dt*tau_syn_inv) + x
    bool z = v > 1.0f;                 // spike_fn(v - 1)
    sh[t * 65536 + n] = z ? (f16)1.f : (f16)0.f;
    v = z ? 0.f : v;                   // reset
  }
}

// ---------------- CUBA LI scan ----------------
__global__ __launch_bounds__(64) void li_scan(const float* __restrict__ co,
                                              float* __restrict__ out) {
  const int n = blockIdx.x * 64 + threadIdx.x;  // 16384 readout neurons
  float v = 0.f, cur = 0.f;
#pragma unroll 4
  for (int t = 0; t < 256; ++t) {
    float x = co[t * 16384 + n];
    v = v + 0.16666667f * (cur - v);
    cur = 0.8333333f * cur + x;
    out[t * 16384 + n] = v;
  }
}

// ---------------- launch ----------------
extern "C" void kernel_launch(void* const* d_in, const int* in_sizes, int n_in,
                              void* d_out, int out_size, void* d_ws, size_t ws_size,
                              hipStream_t stream) {
  const float* spikes = (const float*)d_in[0];    // [256][128][784]
  const float* w_hidden = (const float*)d_in[1];  // [512][784]
  const float* w_out = (const float*)d_in[2];     // [128][512]
  float* out = (float*)d_out;                     // [256][128][128]

  char* ws = (char*)d_ws;
  // layout (bytes):
  //   A16  [32768][800] f16 : 52,428,800   (aliased later by c_o [32768][128] f32)
  //   w2h  [512][1600]  f16 :  1,638,400
  //   c_h  [32768][512] f32 : 67,108,864
  //   s_h  [32768][512] f16 : 33,554,432
  //   w2o  [128][1024]  f16 :    262,144
  // total 154,992,640
  f16* A16 = (f16*)ws;
  float* c_o = (float*)ws;  // alias: A16 dead after GEMM1
  f16* w2h = (f16*)(ws + 52428800);
  float* c_h = (float*)(ws + 52428800 + 1638400);
  f16* s_h = (f16*)(ws + 52428800 + 1638400 + 67108864);
  f16* w2o = (f16*)(ws + 52428800 + 1638400 + 67108864 + 33554432);

  conv_a<<<12800, 256, 0, stream>>>(spikes, A16);
  conv_wh<<<3200, 256, 0, stream>>>(w_hidden, w2h);
  conv_wo<<<512, 256, 0, stream>>>(w_out, w2o);

  // GEMM1: c_h[32768][512] = A16[32768][800] * w2h[512][1600]^T (split K)
  gemm_split2<512, 800, 1600, 25, 800><<<dim3(4, 256), 256, 0, stream>>>(A16, w2h, c_h);

  lif_scan<<<256, 256, 0, stream>>>(c_h, s_h);

  // GEMM2: c_o[32768][128] = s_h[32768][512] * w2o[128][1024]^T (split K)
  gemm_split2<128, 512, 1024, 16, 512><<<dim3(1, 256), 256, 0, stream>>>(s_h, w2o, c_o);

  li_scan<<<256, 64, 0, stream>>>(c_o, out);
}

// Round 2
// 279.252 us; speedup vs baseline: 1.1937x; 1.1937x over previous
//
#include <hip/hip_runtime.h>

typedef _Float16 f16;
typedef _Float16 f16x8 __attribute__((ext_vector_type(8)));
typedef float f32x4 __attribute__((ext_vector_type(4)));

#define GLOBAL_AS __attribute__((address_space(1)))
#define LDS_AS __attribute__((address_space(3)))

// async global->LDS, 16B per lane. LDS dest = wave-uniform base + lane*16.
__device__ __forceinline__ void async16(const void* g, void* l) {
  __builtin_amdgcn_global_load_lds((const GLOBAL_AS unsigned int*)g,
                                   (LDS_AS unsigned int*)l, 16, 0, 0);
}

// ---------------- conversion kernels ----------------

// spikes fp32 [32768][784] -> f16 [32768][800] (pad cols 784..799 = 0)
__global__ __launch_bounds__(256) void conv_a(const float* __restrict__ s,
                                              f16* __restrict__ a16) {
  int idx = blockIdx.x * 256 + threadIdx.x;  // < 3,276,800
  int m = idx / 100;
  int g = idx - m * 100;
  f16x8 h = {};
  if (g < 98) {
    const float4* p = (const float4*)(s + (size_t)m * 784 + g * 8);
    float4 x = p[0];
    float4 y = p[1];
    h[0] = (f16)x.x; h[1] = (f16)x.y; h[2] = (f16)x.z; h[3] = (f16)x.w;
    h[4] = (f16)y.x; h[5] = (f16)y.y; h[6] = (f16)y.z; h[7] = (f16)y.w;
  }
  *(f16x8*)(a16 + (size_t)m * 800 + g * 8) = h;
}

// merged weight conversion:
//  w_hidden [512][784] -> w2h f16 [512][1600] (hi pad->800 | lo*2048 pad->1600)
//  w_out    [128][512] -> w2o f16 [128][1024] (hi | lo*2048)
__global__ __launch_bounds__(256) void conv_w(const float* __restrict__ wh,
                                              const float* __restrict__ wo,
                                              f16* __restrict__ w2h,
                                              f16* __restrict__ w2o) {
  int idx = blockIdx.x * 256 + threadIdx.x;
  if (idx < 819200) {
    int h = idx / 1600;
    int c = idx - h * 1600;
    f16 o = (f16)0.f;
    if (c < 784) {
      o = (f16)wh[h * 784 + c];
    } else if (c >= 800 && c < 1584) {
      float x = wh[h * 784 + (c - 800)];
      f16 hi = (f16)x;
      o = (f16)((x - (float)hi) * 2048.0f);
    }
    w2h[idx] = o;
  } else if (idx < 819200 + 131072) {
    int j = idx - 819200;
    int o_ = j >> 10;
    int c = j & 1023;
    float x = wo[o_ * 512 + (c & 511)];
    f16 hi = (f16)x;
    w2o[j] = (c < 512) ? hi : (f16)((x - (float)hi) * 2048.0f);
  }
}

// ---------------- split-precision f16 MFMA GEMM (combined-phase) ----------------
// C[M][N_LD] = A[M][K] * (B_hi + 2^-11 B_lo)[N][K]^T.
// A chunk staged ONCE per K-step; hi and lo MFMAs run against it into separate
// accumulators; combine at epilogue. 32 MFMA per barrier pair, 128x128 tile.
template <int N_LD, int A_STRIDE, int B_STRIDE, int CHUNKS, int B_OFF_LO>
__global__ __launch_bounds__(256, 2) void gemm_split2(const f16* __restrict__ A,
                                                      const f16* __restrict__ B,
                                                      float* __restrict__ C) {
  __shared__ f16 lds_a[128 * 32];
  __shared__ f16 lds_bh[128 * 32];
  __shared__ f16 lds_bl[128 * 32];
  const int t = threadIdx.x;
  const int lane = t & 63;
  const int wave = t >> 6;
  const int m0 = blockIdx.y * 128;
  const int n0 = blockIdx.x * 128;
  const int wm = (wave >> 1) * 64;
  const int wn = (wave & 1) * 64;
  const int row = lane & 15;
  const int quad = lane >> 4;

  const int ja1 = t, ja2 = t + 256;
  const f16* a_base1 = A + (m0 + (ja1 >> 2)) * A_STRIDE + (ja1 & 3) * 8;
  const f16* a_base2 = A + (m0 + (ja2 >> 2)) * A_STRIDE + (ja2 & 3) * 8;
  const f16* b_base1 = B + (n0 + (ja1 >> 2)) * B_STRIDE + (ja1 & 3) * 8;
  const f16* b_base2 = B + (n0 + (ja2 >> 2)) * B_STRIDE + (ja2 & 3) * 8;

  f32x4 acch[4][4] = {};
  f32x4 accl[4][4] = {};

  for (int c = 0; c < CHUNKS; ++c) {
    const int k0 = c * 32;
    async16(a_base1 + k0, &lds_a[ja1 * 8]);
    async16(a_base2 + k0, &lds_a[ja2 * 8]);
    async16(b_base1 + k0, &lds_bh[ja1 * 8]);
    async16(b_base2 + k0, &lds_bh[ja2 * 8]);
    async16(b_base1 + B_OFF_LO + k0, &lds_bl[ja1 * 8]);
    async16(b_base2 + B_OFF_LO + k0, &lds_bl[ja2 * 8]);
    __syncthreads();
    f16x8 af[4], bh[4], bl[4];
#pragma unroll
    for (int tm = 0; tm < 4; ++tm)
      af[tm] = *(const f16x8*)&lds_a[(wm + tm * 16 + row) * 32 + quad * 8];
#pragma unroll
    for (int tn = 0; tn < 4; ++tn) {
      bh[tn] = *(const f16x8*)&lds_bh[(wn + tn * 16 + row) * 32 + quad * 8];
      bl[tn] = *(const f16x8*)&lds_bl[(wn + tn * 16 + row) * 32 + quad * 8];
    }
#pragma unroll
    for (int tm = 0; tm < 4; ++tm)
#pragma unroll
      for (int tn = 0; tn < 4; ++tn) {
        acch[tm][tn] =
            __builtin_amdgcn_mfma_f32_16x16x32_f16(af[tm], bh[tn], acch[tm][tn], 0, 0, 0);
        accl[tm][tn] =
            __builtin_amdgcn_mfma_f32_16x16x32_f16(af[tm], bl[tn], accl[tm][tn], 0, 0, 0);
      }
    __syncthreads();
  }
  // C/D layout: col = lane&15, row = quad*4 + r
#pragma unroll
  for (int tm = 0; tm < 4; ++tm)
#pragma unroll
    for (int tn = 0; tn < 4; ++tn)
#pragma unroll
      for (int r = 0; r < 4; ++r) {
        const int mm = m0 + wm + tm * 16 + quad * 4 + r;
        const int nn = n0 + wn + tn * 16 + row;
        C[mm * N_LD + nn] = acch[tm][tn][r] + 4.8828125e-4f * accl[tm][tn][r];  // 2^-11
      }
}

// ---------------- CUBA LIF scan (8-deep prefetch) ----------------
__global__ __launch_bounds__(256) void lif_scan(const float* __restrict__ ch,
                                                f16* __restrict__ sh) {
  const int n = blockIdx.x * 256 + threadIdx.x;  // 65536 neurons
  float buf[8];
#pragma unroll
  for (int j = 0; j < 8; ++j) buf[j] = ch[j * 65536 + n];
  float v = 0.f, cur = 0.f;
#pragma unroll 8
  for (int t = 0; t < 256; ++t) {
    float x = buf[t & 7];
    buf[t & 7] = ch[((t + 8) & 255) * 65536 + n];  // wraps: dead loads past t=247
    v = v + 0.16666667f * (cur - v);   // v += dt*tau_mem_inv*(-v+i), old i
    cur = 0.8333333f * cur + x;        // i = i*(1-dt*tau_syn_inv) + x
    bool z = v > 1.0f;                 // spike
    sh[t * 65536 + n] = z ? (f16)1.f : (f16)0.f;
    v = z ? 0.f : v;                   // reset
  }
}

// ---------------- CUBA LI scan (8-deep prefetch) ----------------
__global__ __launch_bounds__(64) void li_scan(const float* __restrict__ co,
                                              float* __restrict__ out) {
  const int n = blockIdx.x * 64 + threadIdx.x;  // 16384 readout neurons
  float buf[8];
#pragma unroll
  for (int j = 0; j < 8; ++j) buf[j] = co[j * 16384 + n];
  float v = 0.f, cur = 0.f;
#pragma unroll 8
  for (int t = 0; t < 256; ++t) {
    float x = buf[t & 7];
    buf[t & 7] = co[((t + 8) & 255) * 16384 + n];
    v = v + 0.16666667f * (cur - v);
    cur = 0.8333333f * cur + x;
    out[t * 16384 + n] = v;
  }
}

// ---------------- launch ----------------
extern "C" void kernel_launch(void* const* d_in, const int* in_sizes, int n_in,
                              void* d_out, int out_size, void* d_ws, size_t ws_size,
                              hipStream_t stream) {
  const float* spikes = (const float*)d_in[0];    // [256][128][784]
  const float* w_hidden = (const float*)d_in[1];  // [512][784]
  const float* w_out = (const float*)d_in[2];     // [128][512]
  float* out = (float*)d_out;                     // [256][128][128]

  char* ws = (char*)d_ws;
  // layout (bytes):
  //   A16  [32768][800] f16 : 52,428,800   (aliased later by c_o [32768][128] f32)
  //   w2h  [512][1600]  f16 :  1,638,400
  //   c_h  [32768][512] f32 : 67,108,864
  //   s_h  [32768][512] f16 : 33,554,432
  //   w2o  [128][1024]  f16 :    262,144
  f16* A16 = (f16*)ws;
  float* c_o = (float*)ws;  // alias: A16 dead after GEMM1
  f16* w2h = (f16*)(ws + 52428800);
  float* c_h = (float*)(ws + 52428800 + 1638400);
  f16* s_h = (f16*)(ws + 52428800 + 1638400 + 67108864);
  f16* w2o = (f16*)(ws + 52428800 + 1638400 + 67108864 + 33554432);

  conv_a<<<12800, 256, 0, stream>>>(spikes, A16);
  conv_w<<<3712, 256, 0, stream>>>(w_hidden, w_out, w2h, w2o);

  // GEMM1: c_h[32768][512] = A16[32768][800] * w2h[512][800hi|800lo]^T
  gemm_split2<512, 800, 1600, 25, 800><<<dim3(4, 256), 256, 0, stream>>>(A16, w2h, c_h);

  lif_scan<<<256, 256, 0, stream>>>(c_h, s_h);

  // GEMM2: c_o[32768][128] = s_h[32768][512] * w2o[128][512hi|512lo]^T
  gemm_split2<128, 512, 1024, 16, 512><<<dim3(1, 256), 256, 0, stream>>>(s_h, w2o, c_o);

  li_scan<<<256, 64, 0, stream>>>(c_o, out);
}

// Round 3
// 267.521 us; speedup vs baseline: 1.2460x; 1.0438x over previous
//
#include <hip/hip_runtime.h>

typedef _Float16 f16;
typedef _Float16 f16x8 __attribute__((ext_vector_type(8)));
typedef float f32x4 __attribute__((ext_vector_type(4)));

#define GLOBAL_AS __attribute__((address_space(1)))
#define LDS_AS __attribute__((address_space(3)))

__device__ __forceinline__ void async16(const void* g, void* l) {
  __builtin_amdgcn_global_load_lds((const GLOBAL_AS unsigned int*)g,
                                   (LDS_AS unsigned int*)l, 16, 0, 0);
}

// ---------------- conversion kernels ----------------

// spikes fp32 [32768][784] -> f16 [32768][800] (pad cols 784..799 = 0)
__global__ __launch_bounds__(256) void conv_a(const float* __restrict__ s,
                                              f16* __restrict__ a16) {
  int idx = blockIdx.x * 256 + threadIdx.x;  // < 3,276,800
  int m = idx / 100;
  int g = idx - m * 100;
  f16x8 h = {};
  if (g < 98) {
    const float4* p = (const float4*)(s + (size_t)m * 784 + g * 8);
    float4 x = p[0];
    float4 y = p[1];
    h[0] = (f16)x.x; h[1] = (f16)x.y; h[2] = (f16)x.z; h[3] = (f16)x.w;
    h[4] = (f16)y.x; h[5] = (f16)y.y; h[6] = (f16)y.z; h[7] = (f16)y.w;
  }
  *(f16x8*)(a16 + (size_t)m * 800 + g * 8) = h;
}

// w_hidden [512][784] -> w2h f16 [512][1600] (hi pad->800 | lo*2048 pad->1600)
// w_out    [128][512] -> w2o f16 [128][512]  (hi only)
__global__ __launch_bounds__(256) void conv_w(const float* __restrict__ wh,
                                              const float* __restrict__ wo,
                                              f16* __restrict__ w2h,
                                              f16* __restrict__ w2o) {
  int idx = blockIdx.x * 256 + threadIdx.x;
  if (idx < 819200) {
    int h = idx / 1600;
    int c = idx - h * 1600;
    f16 o = (f16)0.f;
    if (c < 784) {
      o = (f16)wh[h * 784 + c];
    } else if (c >= 800 && c < 1584) {
      float x = wh[h * 784 + (c - 800)];
      f16 hi = (f16)x;
      o = (f16)((x - (float)hi) * 2048.0f);  // exact residual, scaled past denormals
    }
    w2h[idx] = o;
  } else if (idx < 819200 + 65536) {
    int j = idx - 819200;
    w2o[j] = (f16)wo[j];
  }
}

// ---------------- f16 MFMA GEMM, BK=64, optional lo-plane / 32-tail / K-split --------
// C[M][N_LD] = A[M][K] * B[N][K]^T (+ 2^-11 * A*B_lo^T if B_OFF_LO>0).
// 128x128 tile, 4 waves 2x2, 16x16x32 f16 MFMA. BK=64 => 64(128) MFMA per barrier.
// KSPLIT_SPAN>0: blockIdx.x selects a K-range of that span; C offset by x*M*N_LD.
template <int N_LD, int A_STRIDE, int B_STRIDE, int NCH64, bool TAIL32,
          int B_OFF_LO, int KSPLIT_SPAN>
__global__ __launch_bounds__(256, 2) void gemm_f16(const f16* __restrict__ A,
                                                   const f16* __restrict__ B,
                                                   float* __restrict__ C) {
  constexpr bool HAS_LO = (B_OFF_LO > 0);
  __shared__ f16 lds_a[128 * 64];
  __shared__ f16 lds_bh[128 * 64];
  __shared__ f16 lds_bl[HAS_LO ? 128 * 64 : 8];
  const int t = threadIdx.x;
  const int lane = t & 63;
  const int wave = t >> 6;
  const int m0 = blockIdx.y * 128;
  const int n0 = KSPLIT_SPAN ? 0 : blockIdx.x * 128;
  const int kb = KSPLIT_SPAN ? blockIdx.x * KSPLIT_SPAN : 0;
  float* Cp = KSPLIT_SPAN ? C + (size_t)blockIdx.x * 32768 * N_LD : C;
  const int wm = (wave >> 1) * 64;
  const int wn = (wave & 1) * 64;
  const int row = lane & 15;
  const int quad = lane >> 4;

  f32x4 acch[4][4] = {};
  f32x4 accl[HAS_LO ? 4 : 1][4] = {};

  for (int c = 0; c < NCH64; ++c) {
    const int k0 = kb + c * 64;
#pragma unroll
    for (int s = 0; s < 4; ++s) {
      const int j = t + s * 256;
      const int r = j >> 3, g = (j & 7) * 8;
      async16(A + (m0 + r) * A_STRIDE + k0 + g, &lds_a[j * 8]);
      async16(B + (n0 + r) * B_STRIDE + k0 + g, &lds_bh[j * 8]);
      if (HAS_LO) async16(B + (n0 + r) * B_STRIDE + B_OFF_LO + k0 + g, &lds_bl[j * 8]);
    }
    __syncthreads();
#pragma unroll
    for (int ks = 0; ks < 2; ++ks) {
      f16x8 af[4], bh[4], bl[4];
#pragma unroll
      for (int tm = 0; tm < 4; ++tm)
        af[tm] = *(const f16x8*)&lds_a[(wm + tm * 16 + row) * 64 + ks * 32 + quad * 8];
#pragma unroll
      for (int tn = 0; tn < 4; ++tn) {
        bh[tn] = *(const f16x8*)&lds_bh[(wn + tn * 16 + row) * 64 + ks * 32 + quad * 8];
        if (HAS_LO)
          bl[tn] = *(const f16x8*)&lds_bl[(wn + tn * 16 + row) * 64 + ks * 32 + quad * 8];
      }
#pragma unroll
      for (int tm = 0; tm < 4; ++tm)
#pragma unroll
        for (int tn = 0; tn < 4; ++tn) {
          acch[tm][tn] =
              __builtin_amdgcn_mfma_f32_16x16x32_f16(af[tm], bh[tn], acch[tm][tn], 0, 0, 0);
          if (HAS_LO)
            accl[tm][tn] =
                __builtin_amdgcn_mfma_f32_16x16x32_f16(af[tm], bl[tn], accl[tm][tn], 0, 0, 0);
        }
    }
    __syncthreads();
  }

  if (TAIL32) {  // one 32-wide K tail chunk
    const int k0 = kb + NCH64 * 64;
#pragma unroll
    for (int s = 0; s < 2; ++s) {
      const int j = t + s * 256;
      const int r = j >> 2, g = (j & 3) * 8;
      async16(A + (m0 + r) * A_STRIDE + k0 + g, &lds_a[j * 8]);
      async16(B + (n0 + r) * B_STRIDE + k0 + g, &lds_bh[j * 8]);
      if (HAS_LO) async16(B + (n0 + r) * B_STRIDE + B_OFF_LO + k0 + g, &lds_bl[j * 8]);
    }
    __syncthreads();
    f16x8 af[4], bh[4], bl[4];
#pragma unroll
    for (int tm = 0; tm < 4; ++tm)
      af[tm] = *(const f16x8*)&lds_a[(wm + tm * 16 + row) * 32 + quad * 8];
#pragma unroll
    for (int tn = 0; tn < 4; ++tn) {
      bh[tn] = *(const f16x8*)&lds_bh[(wn + tn * 16 + row) * 32 + quad * 8];
      if (HAS_LO) bl[tn] = *(const f16x8*)&lds_bl[(wn + tn * 16 + row) * 32 + quad * 8];
    }
#pragma unroll
    for (int tm = 0; tm < 4; ++tm)
#pragma unroll
      for (int tn = 0; tn < 4; ++tn) {
        acch[tm][tn] =
            __builtin_amdgcn_mfma_f32_16x16x32_f16(af[tm], bh[tn], acch[tm][tn], 0, 0, 0);
        if (HAS_LO)
          accl[tm][tn] =
              __builtin_amdgcn_mfma_f32_16x16x32_f16(af[tm], bl[tn], accl[tm][tn], 0, 0, 0);
      }
  }

  // C/D layout: col = lane&15, row = quad*4 + r
#pragma unroll
  for (int tm = 0; tm < 4; ++tm)
#pragma unroll
    for (int tn = 0; tn < 4; ++tn)
#pragma unroll
      for (int r = 0; r < 4; ++r) {
        const int mm = m0 + wm + tm * 16 + quad * 4 + r;
        const int nn = n0 + wn + tn * 16 + row;
        float val = acch[tm][tn][r];
        if (HAS_LO) val += 4.8828125e-4f * accl[tm][tn][r];  // 2^-11 exact
        Cp[(size_t)mm * N_LD + nn] = val;
      }
}

// ---------------- CUBA LIF scan (double-buffered batches of 8) ----------------
__global__ __launch_bounds__(256) void lif_scan(const float* __restrict__ ch,
                                                f16* __restrict__ sh) {
  const int n = blockIdx.x * 256 + threadIdx.x;  // 65536 neurons
  float xa[8], xb[8];
#pragma unroll
  for (int j = 0; j < 8; ++j) xa[j] = ch[j * 65536 + n];
  float v = 0.f, cur = 0.f;
  for (int c = 0; c < 32; ++c) {
    const int nc = (c + 1) & 31;  // wrap: chunk-0 reload at c=31 is dead, L2-hot
#pragma unroll
    for (int j = 0; j < 8; ++j) xb[j] = ch[(nc * 8 + j) * 65536 + n];
#pragma unroll
    for (int j = 0; j < 8; ++j) {
      const int t = c * 8 + j;
      float x = xa[j];
      v = v + 0.16666667f * (cur - v);  // v += dt*tau_mem_inv*(-v+i), old i
      cur = 0.8333333f * cur + x;       // i = i*(1-dt*tau_syn_inv) + x
      bool z = v > 1.0f;
      sh[t * 65536 + n] = z ? (f16)1.f : (f16)0.f;
      v = z ? 0.f : v;
    }
#pragma unroll
    for (int j = 0; j < 8; ++j) xa[j] = xb[j];
  }
}

// ---------------- CUBA LI scan: sums two K-split streams ----------------
__global__ __launch_bounds__(64) void li_scan(const float* __restrict__ coA,
                                              const float* __restrict__ coB,
                                              float* __restrict__ out) {
  const int n = blockIdx.x * 64 + threadIdx.x;  // 16384 readout neurons
  float xa[8], xb[8];
#pragma unroll
  for (int j = 0; j < 8; ++j) xa[j] = coA[j * 16384 + n] + coB[j * 16384 + n];
  float v = 0.f, cur = 0.f;
  for (int c = 0; c < 32; ++c) {
    const int nc = (c + 1) & 31;
#pragma unroll
    for (int j = 0; j < 8; ++j)
      xb[j] = coA[(nc * 8 + j) * 16384 + n] + coB[(nc * 8 + j) * 16384 + n];
#pragma unroll
    for (int j = 0; j < 8; ++j) {
      const int t = c * 8 + j;
      v = v + 0.16666667f * (cur - xa[j] * 0.f - v);  // keep form simple below
      // (rewritten plainly:)
      // v = v + 1/6*(cur - v); cur = 5/6*cur + x
      cur = 0.8333333f * cur + xa[j];
      out[t * 16384 + n] = v;
    }
#pragma unroll
    for (int j = 0; j < 8; ++j) xa[j] = xb[j];
  }
}

// ---------------- launch ----------------
extern "C" void kernel_launch(void* const* d_in, const int* in_sizes, int n_in,
                              void* d_out, int out_size, void* d_ws, size_t ws_size,
                              hipStream_t stream) {
  const float* spikes = (const float*)d_in[0];    // [256][128][784]
  const float* w_hidden = (const float*)d_in[1];  // [512][784]
  const float* w_out = (const float*)d_in[2];     // [128][512]
  float* out = (float*)d_out;                     // [256][128][128]

  char* ws = (char*)d_ws;
  // layout (bytes):
  //   A16  [32768][800] f16 : 52,428,800  (later aliased by coA|coB, 2x16,777,216)
  //   w2h  [512][1600]  f16 :  1,638,400
  //   c_h  [32768][512] f32 : 67,108,864
  //   s_h  [32768][512] f16 : 33,554,432
  //   w2o  [128][512]   f16 :    131,072
  f16* A16 = (f16*)ws;
  float* coA = (float*)ws;                    // alias: A16 dead after GEMM1
  float* coB = (float*)(ws + 16777216);
  f16* w2h = (f16*)(ws + 52428800);
  float* c_h = (float*)(ws + 52428800 + 1638400);
  f16* s_h = (f16*)(ws + 52428800 + 1638400 + 67108864);
  f16* w2o = (f16*)(ws + 52428800 + 1638400 + 67108864 + 33554432);

  conv_a<<<12800, 256, 0, stream>>>(spikes, A16);
  conv_w<<<3456, 256, 0, stream>>>(w_hidden, w_out, w2h, w2o);

  // GEMM1: c_h[32768][512] = A16[32768][800] * w2h[512][800hi|800lo]^T, K=12*64+32
  gemm_f16<512, 800, 1600, 12, true, 800, 0>
      <<<dim3(4, 256), 256, 0, stream>>>(A16, w2h, c_h);

  lif_scan<<<256, 256, 0, stream>>>(c_h, s_h);

  // GEMM2: co{A,B}[32768][128] = s_h[32768][512] * w2o[128][512]^T, K-split 2x256
  gemm_f16<128, 512, 512, 4, false, 0, 256>
      <<<dim3(2, 256), 256, 0, stream>>>(s_h, w2o, coA);

  li_scan<<<256, 64, 0, stream>>>(coA, coB, out);
}

// Round 4
// 251.541 us; speedup vs baseline: 1.3252x; 1.0635x over previous
//
#include <hip/hip_runtime.h>

typedef _Float16 f16;
typedef _Float16 f16x8 __attribute__((ext_vector_type(8)));
typedef float f32x4 __attribute__((ext_vector_type(4)));

#define GLOBAL_AS __attribute__((address_space(1)))
#define LDS_AS __attribute__((address_space(3)))

__device__ __forceinline__ void async16(const void* g, void* l) {
  __builtin_amdgcn_global_load_lds((const GLOBAL_AS unsigned int*)g,
                                   (LDS_AS unsigned int*)l, 16, 0, 0);
}

// ---------------- conversion kernels ----------------

// spikes fp32 [32768][784] -> f16 [32768][800] (pad cols 784..799 = 0)
__global__ __launch_bounds__(256) void conv_a(const float* __restrict__ s,
                                              f16* __restrict__ a16) {
  int idx = blockIdx.x * 256 + threadIdx.x;  // < 3,276,800
  int m = idx / 100;
  int g = idx - m * 100;
  f16x8 h = {};
  if (g < 98) {
    const float4* p = (const float4*)(s + (size_t)m * 784 + g * 8);
    float4 x = p[0];
    float4 y = p[1];
    h[0] = (f16)x.x; h[1] = (f16)x.y; h[2] = (f16)x.z; h[3] = (f16)x.w;
    h[4] = (f16)y.x; h[5] = (f16)y.y; h[6] = (f16)y.z; h[7] = (f16)y.w;
  }
  *(f16x8*)(a16 + (size_t)m * 800 + g * 8) = h;
}

// w_hidden [512][784] -> w2h f16 [512][1600] (hi pad->800 | lo*2048 pad->1600)
// w_out    [128][512] -> w2o f16 [128][512]  (hi only)
__global__ __launch_bounds__(256) void conv_w(const float* __restrict__ wh,
                                              const float* __restrict__ wo,
                                              f16* __restrict__ w2h,
                                              f16* __restrict__ w2o) {
  int idx = blockIdx.x * 256 + threadIdx.x;
  if (idx < 819200) {
    int h = idx / 1600;
    int c = idx - h * 1600;
    f16 o = (f16)0.f;
    if (c < 784) {
      o = (f16)wh[h * 784 + c];
    } else if (c >= 800 && c < 1584) {
      float x = wh[h * 784 + (c - 800)];
      f16 hi = (f16)x;
      o = (f16)((x - (float)hi) * 2048.0f);  // exact residual, scaled past denormals
    }
    w2h[idx] = o;
  } else if (idx < 819200 + 65536) {
    int j = idx - 819200;
    w2o[j] = (f16)wo[j];
  }
}

// ---------------- f16 MFMA GEMM, BK=64, XOR-swizzled LDS ----------------
// C[M][N_LD] = A[M][K] * B[N][K]^T (+ 2^-11 * A*B_lo^T if B_OFF_LO>0).
// LDS: row r holds its 8 16B-granules permuted p = g ^ (r&7) so that a quad's
// 16-row ds_read_b128 sweep hits all 32 banks (2 lanes/bank = free).
// XCD_SWZ: 1-D grid of 4*256 blocks, mapped so the 4 n-blocks of one m-tile
// land on the same XCD (A rows read once per XCD L2).
template <int N_LD, int A_STRIDE, int B_STRIDE, int NCH64, bool TAIL32,
          int B_OFF_LO, int KSPLIT_SPAN, bool XCD_SWZ>
__global__ __launch_bounds__(256, 2) void gemm_f16(const f16* __restrict__ A,
                                                   const f16* __restrict__ B,
                                                   float* __restrict__ C) {
  constexpr bool HAS_LO = (B_OFF_LO > 0);
  __shared__ f16 lds_a[128 * 64];
  __shared__ f16 lds_bh[128 * 64];
  __shared__ f16 lds_bl[HAS_LO ? 128 * 64 : 8];
  const int t = threadIdx.x;
  const int lane = t & 63;
  const int wave = t >> 6;
  int bx, by;
  if (XCD_SWZ) {
    const int b = blockIdx.x;
    by = (b & 7) + 8 * (b >> 5);
    bx = (b >> 3) & 3;
  } else {
    bx = blockIdx.x;
    by = blockIdx.y;
  }
  const int m0 = by * 128;
  const int n0 = KSPLIT_SPAN ? 0 : bx * 128;
  const int kb = KSPLIT_SPAN ? bx * KSPLIT_SPAN : 0;
  float* Cp = KSPLIT_SPAN ? C + (size_t)bx * 32768 * N_LD : C;
  const int wm = (wave >> 1) * 64;
  const int wn = (wave & 1) * 64;
  const int row = lane & 15;
  const int quad = lane >> 4;

  f32x4 acch[4][4] = {};
  f32x4 accl[HAS_LO ? 4 : 1][4] = {};

  for (int c = 0; c < NCH64; ++c) {
    const int k0 = kb + c * 64;
#pragma unroll
    for (int s = 0; s < 4; ++s) {
      const int j = t + s * 256;
      const int r = j >> 3;
      const int g = (j & 7) ^ (r & 7);  // xor-swizzled source granule
      async16(A + (m0 + r) * A_STRIDE + k0 + g * 8, &lds_a[j * 8]);
      async16(B + (n0 + r) * B_STRIDE + k0 + g * 8, &lds_bh[j * 8]);
      if (HAS_LO)
        async16(B + (n0 + r) * B_STRIDE + B_OFF_LO + k0 + g * 8, &lds_bl[j * 8]);
    }
    __syncthreads();
#pragma unroll
    for (int ks = 0; ks < 2; ++ks) {
      f16x8 af[4], bh[4], bl[4];
#pragma unroll
      for (int tm = 0; tm < 4; ++tm) {
        const int ra = wm + tm * 16 + row;
        const int p = (ks * 4 + quad) ^ (ra & 7);
        af[tm] = *(const f16x8*)&lds_a[ra * 64 + p * 8];
      }
#pragma unroll
      for (int tn = 0; tn < 4; ++tn) {
        const int rb = wn + tn * 16 + row;
        const int p = (ks * 4 + quad) ^ (rb & 7);
        bh[tn] = *(const f16x8*)&lds_bh[rb * 64 + p * 8];
        if (HAS_LO) bl[tn] = *(const f16x8*)&lds_bl[rb * 64 + p * 8];
      }
#pragma unroll
      for (int tm = 0; tm < 4; ++tm)
#pragma unroll
        for (int tn = 0; tn < 4; ++tn) {
          acch[tm][tn] =
              __builtin_amdgcn_mfma_f32_16x16x32_f16(af[tm], bh[tn], acch[tm][tn], 0, 0, 0);
          if (HAS_LO)
            accl[tm][tn] =
                __builtin_amdgcn_mfma_f32_16x16x32_f16(af[tm], bl[tn], accl[tm][tn], 0, 0, 0);
        }
    }
    __syncthreads();
  }

  if (TAIL32) {  // one 32-wide K tail chunk; rows have 4 granules, swizzle &3
    const int k0 = kb + NCH64 * 64;
#pragma unroll
    for (int s = 0; s < 2; ++s) {
      const int j = t + s * 256;
      const int r = j >> 2;
      const int g = (j & 3) ^ (r & 3);
      async16(A + (m0 + r) * A_STRIDE + k0 + g * 8, &lds_a[j * 8]);
      async16(B + (n0 + r) * B_STRIDE + k0 + g * 8, &lds_bh[j * 8]);
      if (HAS_LO)
        async16(B + (n0 + r) * B_STRIDE + B_OFF_LO + k0 + g * 8, &lds_bl[j * 8]);
    }
    __syncthreads();
    f16x8 af[4], bh[4], bl[4];
#pragma unroll
    for (int tm = 0; tm < 4; ++tm) {
      const int ra = wm + tm * 16 + row;
      const int p = quad ^ (ra & 3);
      af[tm] = *(const f16x8*)&lds_a[ra * 32 + p * 8];
    }
#pragma unroll
    for (int tn = 0; tn < 4; ++tn) {
      const int rb = wn + tn * 16 + row;
      const int p = quad ^ (rb & 3);
      bh[tn] = *(const f16x8*)&lds_bh[rb * 32 + p * 8];
      if (HAS_LO) bl[tn] = *(const f16x8*)&lds_bl[rb * 32 + p * 8];
    }
#pragma unroll
    for (int tm = 0; tm < 4; ++tm)
#pragma unroll
      for (int tn = 0; tn < 4; ++tn) {
        acch[tm][tn] =
            __builtin_amdgcn_mfma_f32_16x16x32_f16(af[tm], bh[tn], acch[tm][tn], 0, 0, 0);
        if (HAS_LO)
          accl[tm][tn] =
              __builtin_amdgcn_mfma_f32_16x16x32_f16(af[tm], bl[tn], accl[tm][tn], 0, 0, 0);
      }
  }

  // C/D layout: col = lane&15, row = quad*4 + r
#pragma unroll
  for (int tm = 0; tm < 4; ++tm)
#pragma unroll
    for (int tn = 0; tn < 4; ++tn)
#pragma unroll
      for (int r = 0; r < 4; ++r) {
        const int mm = m0 + wm + tm * 16 + quad * 4 + r;
        const int nn = n0 + wn + tn * 16 + row;
        float val = acch[tm][tn][r];
        if (HAS_LO) val += 4.8828125e-4f * accl[tm][tn][r];  // 2^-11 exact
        Cp[(size_t)mm * N_LD + nn] = val;
      }
}

// ---------------- CUBA LIF scan (double-buffered batches of 8) ----------------
__global__ __launch_bounds__(256) void lif_scan(const float* __restrict__ ch,
                                                f16* __restrict__ sh) {
  const int n = blockIdx.x * 256 + threadIdx.x;  // 65536 neurons
  float xa[8], xb[8];
#pragma unroll
  for (int j = 0; j < 8; ++j) xa[j] = ch[j * 65536 + n];
  float v = 0.f, cur = 0.f;
  for (int c = 0; c < 32; ++c) {
    const int nc = (c + 1) & 31;  // wrap: chunk-0 reload at c=31 is dead, L2-hot
#pragma unroll
    for (int j = 0; j < 8; ++j) xb[j] = ch[(nc * 8 + j) * 65536 + n];
#pragma unroll
    for (int j = 0; j < 8; ++j) {
      const int t = c * 8 + j;
      float x = xa[j];
      v = v + 0.16666667f * (cur - v);  // v += dt*tau_mem_inv*(-v+i), old i
      cur = 0.8333333f * cur + x;       // i = i*(1-dt*tau_syn_inv) + x
      bool z = v > 1.0f;
      sh[t * 65536 + n] = z ? (f16)1.f : (f16)0.f;
      v = z ? 0.f : v;
    }
#pragma unroll
    for (int j = 0; j < 8; ++j) xa[j] = xb[j];
  }
}

// ---------------- CUBA LI scan, 4-way T-segmented ----------------
// LI is linear; state influence decays (5/6)^d. Each segment warm-runs the
// previous 64 steps from zero state (error < ~4e-3 * |x|), then emits 64
// outputs. 65536 threads vs 16384 -> 4x latency hiding. Sums K-split streams.
__global__ __launch_bounds__(256) void li_scan_seg(const float* __restrict__ coA,
                                                   const float* __restrict__ coB,
                                                   float* __restrict__ out) {
  const int tid = blockIdx.x * 256 + threadIdx.x;  // 65536
  const int n = tid & 16383;
  const int seg = tid >> 14;  // 0..3
  const int t0 = seg * 64;
  float v = 0.f, cur = 0.f;
  float xa[8], xb[8];
  if (seg) {
    const int w0 = t0 - 64;
#pragma unroll
    for (int j = 0; j < 8; ++j)
      xa[j] = coA[(w0 + j) * 16384 + n] + coB[(w0 + j) * 16384 + n];
    for (int c = 0; c < 8; ++c) {
      const int nb = w0 + (c + 1) * 8;  // c==7 prefetches t0..t0+7: seeds output phase
#pragma unroll
      for (int j = 0; j < 8; ++j)
        xb[j] = coA[(nb + j) * 16384 + n] + coB[(nb + j) * 16384 + n];
#pragma unroll
      for (int j = 0; j < 8; ++j) {
        v = v + 0.16666667f * (cur - v);
        cur = 0.8333333f * cur + xa[j];
      }
#pragma unroll
      for (int j = 0; j < 8; ++j) xa[j] = xb[j];
    }
  } else {
#pragma unroll
    for (int j = 0; j < 8; ++j) xa[j] = coA[j * 16384 + n] + coB[j * 16384 + n];
  }
  for (int c = 0; c < 8; ++c) {
    if (c < 7) {
      const int nb = t0 + (c + 1) * 8;
#pragma unroll
      for (int j = 0; j < 8; ++j)
        xb[j] = coA[(nb + j) * 16384 + n] + coB[(nb + j) * 16384 + n];
    }
#pragma unroll
    for (int j = 0; j < 8; ++j) {
      const int t = t0 + c * 8 + j;
      v = v + 0.16666667f * (cur - v);
      cur = 0.8333333f * cur + xa[j];
      out[t * 16384 + n] = v;
    }
#pragma unroll
    for (int j = 0; j < 8; ++j) xa[j] = xb[j];
  }
}

// ---------------- launch ----------------
extern "C" void kernel_launch(void* const* d_in, const int* in_sizes, int n_in,
                              void* d_out, int out_size, void* d_ws, size_t ws_size,
                              hipStream_t stream) {
  const float* spikes = (const float*)d_in[0];    // [256][128][784]
  const float* w_hidden = (const float*)d_in[1];  // [512][784]
  const float* w_out = (const float*)d_in[2];     // [128][512]
  float* out = (float*)d_out;                     // [256][128][128]

  char* ws = (char*)d_ws;
  // layout (bytes):
  //   A16  [32768][800] f16 : 52,428,800  (later aliased by coA|coB, 2x16,777,216)
  //   w2h  [512][1600]  f16 :  1,638,400
  //   c_h  [32768][512] f32 : 67,108,864
  //   s_h  [32768][512] f16 : 33,554,432
  //   w2o  [128][512]   f16 :    131,072
  f16* A16 = (f16*)ws;
  float* coA = (float*)ws;  // alias: A16 dead after GEMM1
  float* coB = (float*)(ws + 16777216);
  f16* w2h = (f16*)(ws + 52428800);
  float* c_h = (float*)(ws + 52428800 + 1638400);
  f16* s_h = (f16*)(ws + 52428800 + 1638400 + 67108864);
  f16* w2o = (f16*)(ws + 52428800 + 1638400 + 67108864 + 33554432);

  conv_a<<<12800, 256, 0, stream>>>(spikes, A16);
  conv_w<<<3456, 256, 0, stream>>>(w_hidden, w_out, w2h, w2o);

  // GEMM1: c_h[32768][512] = A16[32768][800] * w2h[512][800hi|800lo]^T, K=12*64+32
  // 1-D grid, XCD-swizzled so the 4 n-blocks of an m-tile share an XCD's L2.
  gemm_f16<512, 800, 1600, 12, true, 800, 0, true>
      <<<1024, 256, 0, stream>>>(A16, w2h, c_h);

  lif_scan<<<256, 256, 0, stream>>>(c_h, s_h);

  // GEMM2: co{A,B}[32768][128] = s_h[32768][512] * w2o[128][512]^T, K-split 2x256
  gemm_f16<128, 512, 512, 4, false, 0, 256, false>
      <<<dim3(2, 256), 256, 0, stream>>>(s_h, w2o, coA);

  li_scan_seg<<<256, 256, 0, stream>>>(coA, coB, out);
}